// Round 2
// baseline (7000.356 us; speedup 1.0000x reference)
//
#include <hip/hip_runtime.h>
#include <cstdint>

// ---------------- row LayerNorm -> f32 ----------------
template<int C>
__global__ __launch_bounds__(256) void lnf(const float* __restrict__ x, const float* __restrict__ g,
                                           const float* __restrict__ b, float* __restrict__ out){
  constexpr int PT = C/256;
  int row = blockIdx.x;
  const float* xr = x + (size_t)row*C;
  float v[PT]; float s = 0.f, s2 = 0.f;
  #pragma unroll
  for (int j=0;j<PT;j++){ v[j] = xr[threadIdx.x + j*256]; s += v[j]; s2 += v[j]*v[j]; }
  #pragma unroll
  for (int o=32;o;o>>=1){ s += __shfl_xor(s,o); s2 += __shfl_xor(s2,o); }
  __shared__ float ls[4], ls2[4];
  if ((threadIdx.x&63)==0){ ls[threadIdx.x>>6]=s; ls2[threadIdx.x>>6]=s2; }
  __syncthreads();
  s = ls[0]+ls[1]+ls[2]+ls[3]; s2 = ls2[0]+ls2[1]+ls2[2]+ls2[3];
  float mean = s*(1.f/C);
  float var  = s2*(1.f/C) - mean*mean;
  float rstd = 1.0f/sqrtf(var + 1e-5f);
  float* orow = out + (size_t)row*C;
  #pragma unroll
  for (int j=0;j<PT;j++){
    int c = threadIdx.x + j*256;
    orow[c] = (v[j]-mean)*rstd*g[c] + b[c];
  }
}

// ---------------- deterministic row sum: denom[row] = sum_n E[row][n], n<4096 ----------------
__global__ __launch_bounds__(256) void rowsum(const float* __restrict__ E, float* __restrict__ denom){
  int row = blockIdx.x*4 + (threadIdx.x>>6);
  int lane = threadIdx.x & 63;
  const float4* er = (const float4*)(E + (size_t)row*4096);
  float s = 0.f;
  #pragma unroll
  for (int j=0;j<16;j++){
    float4 t = er[j*64 + lane];
    s += t.x + t.y + t.z + t.w;
  }
  #pragma unroll
  for (int o=32;o;o>>=1) s += __shfl_xor(s,o);
  if (lane==0) denom[row] = s;
}

// ---------------- f32 GEMM, 128x128 tile, BK=16, 8x8/thread ----------------
// NT modes (PROJ/SCORE/OUTF): C[m,n] = sum_k A[m,k]*B[n,k]   (B row-major N x K)
// NN mode:                    C[m,n] = sum_k A[m,k]*B[k,n]   (B row-major K x N)
enum { M_PROJ=0, M_SCORE=1, M_NN=2, M_OUTF=3 };

template<int MODE>
__global__ __launch_bounds__(256) void g32(
    const float* __restrict__ A, const float* __restrict__ B, float* __restrict__ C,
    const float* __restrict__ bias, const float* __restrict__ denom,
    int K, int ldA, int ldB, int ldC, int bhBase)
{
  __shared__ float At[16][132];
  __shared__ float Bt[16][132];
  const float* Ap = A; const float* Bp = B; float* Cp = C; const float* dn = denom;
  if (MODE==M_SCORE){
    int bh = bhBase + blockIdx.z; int bb = bh>>2, h = bh&3;
    Ap += (size_t)bb*1024*ldA + (size_t)h*256;       // xi slice (1024 x 256)
    Bp += (size_t)h*256;                             // K slice  (4096 x 256), ld 1024
    Cp += (size_t)blockIdx.z*1024*4096;              // E chunk
  } else if (MODE==M_NN){
    int bh = bhBase + blockIdx.z; int bb = bh>>2, h = bh&3;
    Ap += (size_t)blockIdx.z*1024*4096;              // E chunk (1024 x 4096)
    Bp += (size_t)h*256;                             // K/V cols slice: B[k,n] = W[k*1024 + h*256 + n]
    Cp += (size_t)bb*1024*ldC + (size_t)h*256;       // xi/as slice
    dn += (size_t)blockIdx.z*1024;
  }
  const int tid = threadIdx.x;
  const int tx = tid & 15, ty = tid >> 4;
  const int m0 = blockIdx.y*128, n0 = blockIdx.x*128;

  float acc[8][8] = {};

  for (int k0 = 0; k0 < K; k0 += 16){
    // stage A^T : At[k][m]
    {
      int row = tid>>1, ks = (tid&1)*8;
      const float* src = Ap + (size_t)(m0+row)*ldA + k0 + ks;
      float4 v0 = *(const float4*)src;
      float4 v1 = *(const float4*)(src+4);
      At[ks+0][row]=v0.x; At[ks+1][row]=v0.y; At[ks+2][row]=v0.z; At[ks+3][row]=v0.w;
      At[ks+4][row]=v1.x; At[ks+5][row]=v1.y; At[ks+6][row]=v1.z; At[ks+7][row]=v1.w;
    }
    // stage B into Bt[k][n]
    if (MODE==M_NN){
      int kk = tid>>4, cs = (tid&15)*8;
      const float* src = Bp + (size_t)(k0+kk)*ldB + n0 + cs;
      float4 v0 = *(const float4*)src;
      float4 v1 = *(const float4*)(src+4);
      *(float4*)&Bt[kk][cs]   = v0;
      *(float4*)&Bt[kk][cs+4] = v1;
    } else {
      int row = tid>>1, ks = (tid&1)*8;
      const float* src = Bp + (size_t)(n0+row)*ldB + k0 + ks;
      float4 v0 = *(const float4*)src;
      float4 v1 = *(const float4*)(src+4);
      Bt[ks+0][row]=v0.x; Bt[ks+1][row]=v0.y; Bt[ks+2][row]=v0.z; Bt[ks+3][row]=v0.w;
      Bt[ks+4][row]=v1.x; Bt[ks+5][row]=v1.y; Bt[ks+6][row]=v1.z; Bt[ks+7][row]=v1.w;
    }
    __syncthreads();
    #pragma unroll
    for (int kk=0; kk<16; kk++){
      float a[8], bv[8];
      *(float4*)&a[0]  = *(const float4*)&At[kk][ty*8];
      *(float4*)&a[4]  = *(const float4*)&At[kk][ty*8+4];
      *(float4*)&bv[0] = *(const float4*)&Bt[kk][tx*8];
      *(float4*)&bv[4] = *(const float4*)&Bt[kk][tx*8+4];
      #pragma unroll
      for (int i=0;i<8;i++)
        #pragma unroll
        for (int j=0;j<8;j++)
          acc[i][j] = fmaf(a[i], bv[j], acc[i][j]);
    }
    __syncthreads();
  }

  // epilogue
  #pragma unroll
  for (int i=0;i<8;i++){
    int m = m0 + ty*8 + i;
    float* crow = Cp + (size_t)m*ldC + n0 + tx*8;
    float o[8];
    #pragma unroll
    for (int j=0;j<8;j++){
      float x = acc[i][j];
      if (MODE==M_PROJ || MODE==M_OUTF) x += bias[n0 + tx*8 + j];
      if (MODE==M_SCORE)                x = expf(0.5f*x);
      if (MODE==M_NN)                   x = x / dn[m];
      o[j] = x;
    }
    *(float4*)crow     = *(float4*)&o[0];
    *(float4*)(crow+4) = *(float4*)&o[4];
  }
}

// ---------------- launch ----------------
extern "C" void kernel_launch(void* const* d_in, const int* in_sizes, int n_in,
                              void* d_out, int out_size, void* d_ws, size_t ws_size,
                              hipStream_t stream)
{
  const float* hidden   = (const float*)d_in[0];
  const float* memoryp  = (const float*)d_in[1];
  const float* Wq = (const float*)d_in[2];  const float* bq = (const float*)d_in[3];
  const float* Wk = (const float*)d_in[4];  const float* bk = (const float*)d_in[5];
  const float* Wv = (const float*)d_in[6];  const float* bv = (const float*)d_in[7];
  const float* Wo = (const float*)d_in[8];  const float* bo = (const float*)d_in[9];
  const float* g_stored = (const float*)d_in[10]; const float* b_stored = (const float*)d_in[11];
  const float* g_state  = (const float*)d_in[12]; const float* b_state  = (const float*)d_in[13];
  const float* g_proj   = (const float*)d_in[14]; const float* b_proj   = (const float*)d_in[15];

  char* ws = (char*)d_ws;
  // persistent f32 buffers
  float* xi  = (float*)(ws);                         // 4096 x 1024  (q, then xi updates)
  float* kf  = xi  + 4096ull*1024;                   // 4096 x 1024  (keys, all heads)
  float* vf  = kf  + 4096ull*1024;                   // 4096 x 1024  (values)
  float* asb = vf  + 4096ull*1024;                   // 4096 x 1024  (readout)
  size_t persist = 4ull*4096*1024*4;                 // 64 MB

  // setup overlay (dead after projections)
  float* stateN  = (float*)(ws + persist);           // 4096 x 2048  (32 MB)
  float* storedN = stateN  + 4096ull*2048;           // 4096 x 768   (12 MB)
  float* projN   = storedN + 4096ull*768;            // 4096 x 768   (12 MB)

  // rounds overlay: E + denom
  const size_t SZ_E = 1024ull*4096*4;                // 16 MB per (b,h)
  int nbh = 16;
  while (nbh > 1 && persist + (size_t)nbh*SZ_E + (size_t)nbh*1024*4 > ws_size) nbh >>= 1;
  int NC = 16 / nbh;
  float* E     = (float*)(ws + persist);
  float* denom = E + (size_t)nbh*1024*4096;

  // 1) layernorms (f32 out)
  lnf<2048><<<4096, 256, 0, stream>>>(hidden,  g_state,  b_state,  stateN);
  lnf<768> <<<4096, 256, 0, stream>>>(memoryp, g_stored, b_stored, storedN);
  lnf<768> <<<4096, 256, 0, stream>>>(memoryp, g_proj,   b_proj,   projN);

  // 2) projections (f32, weights used directly from d_in, NT form)
  g32<M_PROJ><<<dim3(8,32,1), 256, 0, stream>>>(stateN,  Wq, xi, bq, nullptr, 2048, 2048, 2048, 1024, 0);
  g32<M_PROJ><<<dim3(8,32,1), 256, 0, stream>>>(storedN, Wk, kf, bk, nullptr,  768,  768,  768, 1024, 0);
  g32<M_PROJ><<<dim3(8,32,1), 256, 0, stream>>>(projN,   Wv, vf, bv, nullptr,  768,  768,  768, 1024, 0);

  // 3) Hopfield rounds: 3 updates with K, then readout with V.
  //    (convergence freeze dropped: diff <= 1e-4 over 512-norm is numerically void)
  for (int r = 0; r < 4; r++){
    const float* W = (r < 3) ? kf : vf;
    float* dst = (r < 3) ? xi : asb;
    for (int c = 0; c < NC; c++){
      int bhBase = c*nbh;
      g32<M_SCORE><<<dim3(32,8,nbh), 256, 0, stream>>>(xi, kf, E, nullptr, nullptr, 256, 1024, 1024, 4096, bhBase);
      rowsum<<<nbh*256, 256, 0, stream>>>(E, denom);
      g32<M_NN><<<dim3(2,8,nbh), 256, 0, stream>>>(E, W, dst, nullptr, denom, 4096, 4096, 1024, 1024, bhBase);
    }
  }

  // 4) output projection -> f32 d_out
  g32<M_OUTF><<<dim3(16,32,1), 256, 0, stream>>>(asb, Wo, (float*)d_out, bo, nullptr, 1024, 1024, 1024, 2048, 0);
}

// Round 3
// 1736.729 us; speedup vs baseline: 4.0308x; 4.0308x over previous
//
#include <hip/hip_runtime.h>
#include <cstdint>

typedef _Float16 f16;
typedef __attribute__((ext_vector_type(8))) _Float16 f16x8;
typedef __attribute__((ext_vector_type(4))) float f32x4;

#define GLDS16(gp, lp) __builtin_amdgcn_global_load_lds( \
  (const __attribute__((address_space(1))) void*)(gp), \
  (__attribute__((address_space(3))) void*)(lp), 16, 0, 0)

__device__ __forceinline__ int swzf(int row){ return (row + (row>>3)) & 7; }

// ---------------- row LayerNorm -> split f16 pair ----------------
template<int C>
__global__ __launch_bounds__(256) void lnf(const float* __restrict__ x, const float* __restrict__ g,
                                           const float* __restrict__ b, f16* __restrict__ o1, f16* __restrict__ o2){
  constexpr int PT = C/256;
  int row = blockIdx.x;
  const float* xr = x + (size_t)row*C;
  float v[PT]; float s = 0.f, s2 = 0.f;
  #pragma unroll
  for (int j=0;j<PT;j++){ v[j] = xr[threadIdx.x + j*256]; s += v[j]; s2 += v[j]*v[j]; }
  #pragma unroll
  for (int o=32;o;o>>=1){ s += __shfl_xor(s,o); s2 += __shfl_xor(s2,o); }
  __shared__ float ls[4], ls2[4];
  if ((threadIdx.x&63)==0){ ls[threadIdx.x>>6]=s; ls2[threadIdx.x>>6]=s2; }
  __syncthreads();
  s = ls[0]+ls[1]+ls[2]+ls[3]; s2 = ls2[0]+ls2[1]+ls2[2]+ls2[3];
  float mean = s*(1.f/C);
  float rstd = 1.0f/sqrtf(s2*(1.f/C) - mean*mean + 1e-5f);
  #pragma unroll
  for (int j=0;j<PT;j++){
    int c = threadIdx.x + j*256;
    float y = (v[j]-mean)*rstd*g[c] + b[c];
    f16 a = (f16)y;
    o1[(size_t)row*C + c] = a;
    o2[(size_t)row*C + c] = (f16)(y - (float)a);
  }
}

// ---------------- f32 -> split f16 pair ----------------
__global__ __launch_bounds__(256) void wsplit(const float* __restrict__ w, f16* __restrict__ o1,
                                              f16* __restrict__ o2, int n){
  for (int i = blockIdx.x*256 + threadIdx.x; i < n; i += gridDim.x*256){
    float x = w[i]; f16 a = (f16)x;
    o1[i] = a; o2[i] = (f16)(x - (float)a);
  }
}

// ---------------- pair transpose: (R,C) -> (C,R), re-split ----------------
__global__ __launch_bounds__(256) void tposeS(const f16* __restrict__ i1, const f16* __restrict__ i2,
                                              f16* __restrict__ o1, f16* __restrict__ o2, int R, int C){
  __shared__ float t[64][65];
  int r0 = blockIdx.y*64, c0 = blockIdx.x*64;
  int row = threadIdx.x>>2, seg = threadIdx.x&3;
  const f16* s1 = i1 + (size_t)(r0+row)*C + c0 + seg*16;
  const f16* s2 = i2 + (size_t)(r0+row)*C + c0 + seg*16;
  f16x8 a0 = *(const f16x8*)s1, a1 = *(const f16x8*)(s1+8);
  f16x8 b0 = *(const f16x8*)s2, b1 = *(const f16x8*)(s2+8);
  #pragma unroll
  for (int e=0;e<8;e++){
    t[row][seg*16+e]   = (float)a0[e] + (float)b0[e];
    t[row][seg*16+8+e] = (float)a1[e] + (float)b1[e];
  }
  __syncthreads();
  f16 p1[16], p2[16];
  #pragma unroll
  for (int e=0;e<16;e++){
    float x = t[seg*16+e][row];
    f16 a = (f16)x; p1[e] = a; p2[e] = (f16)(x - (float)a);
  }
  f16* d1 = o1 + (size_t)(c0+row)*R + r0 + seg*16;
  f16* d2 = o2 + (size_t)(c0+row)*R + r0 + seg*16;
  *(f16x8*)d1 = *(f16x8*)&p1[0]; *(f16x8*)(d1+8) = *(f16x8*)&p1[8];
  *(f16x8*)d2 = *(f16x8*)&p2[0]; *(f16x8*)(d2+8) = *(f16x8*)&p2[8];
}

// ---------------- invden from block partials ----------------
__global__ __launch_bounds__(256) void dinv(const float* __restrict__ denomP, float* __restrict__ invden, int n){
  int i = blockIdx.x*256 + threadIdx.x;
  if (i >= n) return;
  const float* p = denomP + (size_t)i*32;
  float s = 0.f;
  #pragma unroll
  for (int j=0;j<32;j++) s += p[j];
  invden[i] = 1.0f/s;
}

// ---------------- combine K-split partials -> split xi/as pair ----------------
__global__ __launch_bounds__(256) void ucomb(const float* __restrict__ part, f16* __restrict__ o1,
                                             f16* __restrict__ o2, int bhBase){
  int idx = blockIdx.x*256 + threadIdx.x;
  int n = idx & 255, m = (idx>>8) & 1023, zc = idx>>18;
  float v = (part[((size_t)(zc*2+0)*1024 + m)*256 + n] +
             part[((size_t)(zc*2+1)*1024 + m)*256 + n]) * (1.0f/4096.0f);
  int bh = bhBase + zc, bb = bh>>2, h = bh&3;
  size_t off = ((size_t)(bb*1024+m))*1024 + (size_t)h*256 + n;
  f16 a = (f16)v;
  o1[off] = a; o2[off] = (f16)(v - (float)a);
}

// ---------------- split-f16 GEMM (f32-accurate), 128x128 tile, BK=32 ----------------
// C[m,n] = sum_k A[m,k]*B[n,k]  (both operands stored as f16 pairs, NT form)
enum { M_PROJ=0, M_SCORE=1, M_UPD=2, M_OUT=3 };

template<int MODE>
__global__ __launch_bounds__(256) void sg(
    const f16* __restrict__ A1, const f16* __restrict__ A2,
    const f16* __restrict__ B1, const f16* __restrict__ B2,
    const float* __restrict__ Ef, const float* __restrict__ invden,
    const float* __restrict__ bias,
    float* __restrict__ Cf, f16* __restrict__ C1, f16* __restrict__ C2,
    float* __restrict__ denomP,
    int K, int ldA, int ldB, int ldC, int bhBase)
{
  __shared__ __align__(16) char lds[32768];
  const f16 *pA1=A1, *pA2=A2, *pB1=B1, *pB2=B2;
  const float* pE = Ef; const float* pInv = invden;
  float* pCf = Cf; f16 *pC1=C1, *pC2=C2; float* pDen = denomP;

  if (MODE==M_SCORE){
    int bh = bhBase + blockIdx.z, bb = bh>>2, h = bh&3;
    pA1 += (size_t)bb*1024*ldA + (size_t)h*256;
    pA2 += (size_t)bb*1024*ldA + (size_t)h*256;
    pB1 += (size_t)h*256;  pB2 += (size_t)h*256;
    pCf += (size_t)blockIdx.z*1024*4096;
    pDen += (size_t)blockIdx.z*1024*32;
  } else if (MODE==M_UPD){
    int z0 = blockIdx.z, zc = z0>>1, sp = z0&1;
    int bh = bhBase + zc, h = bh&3;
    pE  += (size_t)zc*1024*4096 + (size_t)sp*2048;
    pB1 += (size_t)h*256*4096 + (size_t)sp*2048;
    pB2 += (size_t)h*256*4096 + (size_t)sp*2048;
    pInv += (size_t)zc*1024;
    pCf += (size_t)z0*1024*256;
  }

  const int tid = threadIdx.x;
  const int lane = tid & 63, w = tid >> 6;
  const int wr = w>>1, wc = w&1;
  const int g = lane>>4, li = lane&15;
  const int m0 = blockIdx.y*128, n0 = blockIdx.x*128;

  f32x4 acc[4][4] = {};

  for (int k0 = 0; k0 < K; k0 += 32){
    // ---- stage A ----
    if (MODE==M_UPD){
      int srow = tid>>1, ss = tid&1;
      float iv = pInv[m0+srow] * 4096.0f;
      const float* es = pE + (size_t)(m0+srow)*4096 + k0 + ss*16;
      f32x4 e0 = ((const f32x4*)es)[0] * iv;
      f32x4 e1 = ((const f32x4*)es)[1] * iv;
      f32x4 e2 = ((const f32x4*)es)[2] * iv;
      f32x4 e3 = ((const f32x4*)es)[3] * iv;
      float wv[16];
      *(f32x4*)&wv[0]=e0; *(f32x4*)&wv[4]=e1; *(f32x4*)&wv[8]=e2; *(f32x4*)&wv[12]=e3;
      f16 h1[16], h2[16];
      #pragma unroll
      for (int j=0;j<16;j++){ float x = wv[j]; f16 a=(f16)x; h1[j]=a; h2[j]=(f16)(x-(float)a); }
      int sz = swzf(srow);
      char* rb = lds + srow*128;
      *(f16x8*)(rb + (((ss*2+0)^sz)<<4)) = *(f16x8*)&h1[0];
      *(f16x8*)(rb + (((ss*2+1)^sz)<<4)) = *(f16x8*)&h1[8];
      *(f16x8*)(rb + (((4+ss*2+0)^sz)<<4)) = *(f16x8*)&h2[0];
      *(f16x8*)(rb + (((4+ss*2+1)^sz)<<4)) = *(f16x8*)&h2[8];
    } else {
      #pragma unroll
      for (int it=0; it<4; it++){
        int c = tid + it*256, row = c>>3, sub = c&7;
        int q = sub ^ swzf(row);
        const f16* src = ((q&4) ? pA2 : pA1) + (size_t)(m0+row)*ldA + k0 + (q&3)*8;
        GLDS16(src, lds + c*16);
      }
    }
    // ---- stage B (always GLDS) ----
    #pragma unroll
    for (int it=0; it<4; it++){
      int c = tid + it*256, row = c>>3, sub = c&7;
      int q = sub ^ swzf(row);
      const f16* src = ((q&4) ? pB2 : pB1) + (size_t)(n0+row)*ldB + k0 + (q&3)*8;
      GLDS16(src, lds + 16384 + c*16);
    }
    __syncthreads();
    // ---- fragments + 48 MFMA ----
    f16x8 a1[4], a2[4], b1v[4], b2v[4];
    #pragma unroll
    for (int mi=0;mi<4;mi++){
      int r = wr*64 + mi*16 + li; int sz = swzf(r);
      const char* p = lds + r*128;
      a1[mi] = *(const f16x8*)(p + ((g^sz)<<4));
      a2[mi] = *(const f16x8*)(p + (((4+g)^sz)<<4));
    }
    #pragma unroll
    for (int nj=0;nj<4;nj++){
      int r = wc*64 + nj*16 + li; int sz = swzf(r);
      const char* p = lds + 16384 + r*128;
      b1v[nj] = *(const f16x8*)(p + ((g^sz)<<4));
      b2v[nj] = *(const f16x8*)(p + (((4+g)^sz)<<4));
    }
    #pragma unroll
    for (int mi=0;mi<4;mi++)
      #pragma unroll
      for (int nj=0;nj<4;nj++){
        acc[mi][nj] = __builtin_amdgcn_mfma_f32_16x16x32_f16(a1[mi], b1v[nj], acc[mi][nj],0,0,0);
        acc[mi][nj] = __builtin_amdgcn_mfma_f32_16x16x32_f16(a2[mi], b1v[nj], acc[mi][nj],0,0,0);
        acc[mi][nj] = __builtin_amdgcn_mfma_f32_16x16x32_f16(a1[mi], b2v[nj], acc[mi][nj],0,0,0);
      }
    __syncthreads();
  }

  // ---- epilogue ----
  float rs[4][4];
  if (MODE==M_SCORE){
    #pragma unroll
    for (int mi=0;mi<4;mi++)
      #pragma unroll
      for (int r=0;r<4;r++) rs[mi][r]=0.f;
  }
  #pragma unroll
  for (int mi=0;mi<4;mi++){
    int mrow = m0 + wr*64 + mi*16 + g*4;
    #pragma unroll
    for (int nj=0;nj<4;nj++){
      int n = n0 + wc*64 + nj*16 + li;
      f32x4 a = acc[mi][nj];
      if (MODE==M_PROJ){
        float bvv = bias[n];
        #pragma unroll
        for (int r=0;r<4;r++){
          float y = a[r]+bvv; f16 y1=(f16)y;
          pC1[(size_t)(mrow+r)*ldC + n] = y1;
          pC2[(size_t)(mrow+r)*ldC + n] = (f16)(y-(float)y1);
        }
      } else if (MODE==M_SCORE){
        #pragma unroll
        for (int r=0;r<4;r++){
          float e = expf(0.5f*a[r]);
          pCf[(size_t)(mrow+r)*ldC + n] = e;
          rs[mi][r] += e;
        }
      } else if (MODE==M_UPD){
        #pragma unroll
        for (int r=0;r<4;r++) pCf[(size_t)(mrow+r)*ldC + n] = a[r];
      } else {
        float bvv = bias[n];
        #pragma unroll
        for (int r=0;r<4;r++) pCf[(size_t)(mrow+r)*ldC + n] = a[r]+bvv;
      }
    }
  }
  if (MODE==M_SCORE){
    #pragma unroll
    for (int mi=0;mi<4;mi++)
      #pragma unroll
      for (int r=0;r<4;r++){
        float s = rs[mi][r];
        s += __shfl_xor(s,1); s += __shfl_xor(s,2); s += __shfl_xor(s,4); s += __shfl_xor(s,8);
        rs[mi][r] = s;
      }
    __syncthreads();
    float* sb = (float*)lds;
    if (li==0){
      #pragma unroll
      for (int mi=0;mi<4;mi++)
        #pragma unroll
        for (int r=0;r<4;r++)
          sb[wc*128 + wr*64 + mi*16 + g*4 + r] = rs[mi][r];
    }
    __syncthreads();
    if (tid < 128) pDen[(size_t)(m0+tid)*32 + blockIdx.x] = sb[tid] + sb[128+tid];
  }
}

// ---------------- launch ----------------
extern "C" void kernel_launch(void* const* d_in, const int* in_sizes, int n_in,
                              void* d_out, int out_size, void* d_ws, size_t ws_size,
                              hipStream_t stream)
{
  const float* hidden   = (const float*)d_in[0];
  const float* memoryp  = (const float*)d_in[1];
  const float* Wq = (const float*)d_in[2];  const float* bq = (const float*)d_in[3];
  const float* Wk = (const float*)d_in[4];  const float* bk = (const float*)d_in[5];
  const float* Wv = (const float*)d_in[6];  const float* bv = (const float*)d_in[7];
  const float* Wo = (const float*)d_in[8];  const float* bo = (const float*)d_in[9];
  const float* g_stored = (const float*)d_in[10]; const float* b_stored = (const float*)d_in[11];
  const float* g_state  = (const float*)d_in[12]; const float* b_state  = (const float*)d_in[13];
  const float* g_proj   = (const float*)d_in[14]; const float* b_proj   = (const float*)d_in[15];

  char* ws = (char*)d_ws;
  size_t off = 0;
  auto alloc = [&](size_t bytes)->char* {
    char* p = ws + off; off += (bytes + 255) & ~(size_t)255; return p;
  };
  const size_t E16 = 4096ull*1024*2;   // bytes of one 4096x1024 f16 array
  f16* xi1 = (f16*)alloc(E16);  f16* xi2 = (f16*)alloc(E16);
  f16* k1  = (f16*)alloc(E16);  f16* k2  = (f16*)alloc(E16);
  f16* kt1 = (f16*)alloc(E16);  f16* kt2 = (f16*)alloc(E16);
  f16* vt1 = (f16*)alloc(E16);  f16* vt2 = (f16*)alloc(E16);
  f16* as1 = (f16*)alloc(E16);  f16* as2 = (f16*)alloc(E16);
  f16* wq1 = (f16*)alloc(1024ull*2048*2); f16* wq2 = (f16*)alloc(1024ull*2048*2);
  f16* wk1 = (f16*)alloc(1024ull*768*2);  f16* wk2 = (f16*)alloc(1024ull*768*2);
  f16* wv1 = (f16*)alloc(1024ull*768*2);  f16* wv2 = (f16*)alloc(1024ull*768*2);
  f16* wo1 = (f16*)alloc(2048ull*1024*2); f16* wo2 = (f16*)alloc(2048ull*1024*2);
  size_t persist = off;

  // setup overlay
  size_t o2 = persist;
  auto alloc2 = [&](size_t bytes)->char* {
    char* p = ws + o2; o2 += (bytes + 255) & ~(size_t)255; return p;
  };
  f16* sn1 = (f16*)alloc2(4096ull*2048*2); f16* sn2 = (f16*)alloc2(4096ull*2048*2);
  f16* st1 = (f16*)alloc2(4096ull*768*2);  f16* st2 = (f16*)alloc2(4096ull*768*2);
  f16* pj1 = (f16*)alloc2(4096ull*768*2);  f16* pj2 = (f16*)alloc2(4096ull*768*2);
  f16* v1  = (f16*)alloc2(E16);            f16* v2  = (f16*)alloc2(E16);

  // rounds overlay (reuses setup space)
  int nbh = 8;
  while (nbh > 1){
    size_t need = persist + (size_t)nbh*(1024ull*4096*4) + (size_t)nbh*(2*1024*256*4)
                + (size_t)nbh*(1024*32*4) + (size_t)nbh*1024*4 + 4096;
    if (need <= ws_size) break;
    nbh >>= 1;
  }
  int NC = 16 / nbh;
  o2 = persist;
  float* E      = (float*)alloc2((size_t)nbh*1024*4096*4);
  float* part   = (float*)alloc2((size_t)nbh*2*1024*256*4);
  float* denomP = (float*)alloc2((size_t)nbh*1024*32*4);
  float* invden = (float*)alloc2((size_t)nbh*1024*4);

  // 1) layernorms -> split pairs
  lnf<2048><<<4096, 256, 0, stream>>>(hidden,  g_state,  b_state,  sn1, sn2);
  lnf<768> <<<4096, 256, 0, stream>>>(memoryp, g_stored, b_stored, st1, st2);
  lnf<768> <<<4096, 256, 0, stream>>>(memoryp, g_proj,   b_proj,   pj1, pj2);
  // 2) weight splits
  wsplit<<<2048, 256, 0, stream>>>(Wq, wq1, wq2, 1024*2048);
  wsplit<<<1024, 256, 0, stream>>>(Wk, wk1, wk2, 1024*768);
  wsplit<<<1024, 256, 0, stream>>>(Wv, wv1, wv2, 1024*768);
  wsplit<<<2048, 256, 0, stream>>>(Wo, wo1, wo2, 2048*1024);
  // 3) projections (NT): q->xi pair, k->k pair, v->v pair
  sg<M_PROJ><<<dim3(8,32,1),256,0,stream>>>(sn1,sn2, wq1,wq2, nullptr,nullptr, bq, nullptr, xi1,xi2, nullptr, 2048,2048,2048,1024,0);
  sg<M_PROJ><<<dim3(8,32,1),256,0,stream>>>(st1,st2, wk1,wk2, nullptr,nullptr, bk, nullptr, k1,k2,  nullptr,  768, 768, 768,1024,0);
  sg<M_PROJ><<<dim3(8,32,1),256,0,stream>>>(pj1,pj2, wv1,wv2, nullptr,nullptr, bv, nullptr, v1,v2,  nullptr,  768, 768, 768,1024,0);
  // 4) transposes: (4096x1024) -> (1024x4096), re-split
  tposeS<<<dim3(16,64),256,0,stream>>>(k1,k2, kt1,kt2, 4096,1024);
  tposeS<<<dim3(16,64),256,0,stream>>>(v1,v2, vt1,vt2, 4096,1024);
  // 5) Hopfield rounds: 3 updates with K^T, readout with V^T
  //    (convergence freeze dropped: diff<=1e-4 over 512-norm is numerically void)
  for (int r = 0; r < 4; r++){
    const f16* Bt1 = (r < 3) ? kt1 : vt1;
    const f16* Bt2 = (r < 3) ? kt2 : vt2;
    f16* d1 = (r < 3) ? xi1 : as1;
    f16* d2 = (r < 3) ? xi2 : as2;
    for (int c = 0; c < NC; c++){
      int bhBase = c*nbh;
      sg<M_SCORE><<<dim3(32,8,nbh),256,0,stream>>>(xi1,xi2, k1,k2, nullptr,nullptr, nullptr, E, nullptr,nullptr, denomP, 256,1024,1024,4096, bhBase);
      dinv<<<(nbh*1024+255)/256,256,0,stream>>>(denomP, invden, nbh*1024);
      sg<M_UPD><<<dim3(2,8,nbh*2),256,0,stream>>>(nullptr,nullptr, Bt1,Bt2, E, invden, nullptr, part, nullptr,nullptr, nullptr, 2048,0,4096,256, bhBase);
      ucomb<<<nbh*1024,256,0,stream>>>(part, d1, d2, bhBase);
    }
  }
  // 6) output projection -> f32 d_out
  sg<M_OUT><<<dim3(16,32,1),256,0,stream>>>(as1,as2, wo1,wo2, nullptr,nullptr, bo, (float*)d_out, nullptr,nullptr, nullptr, 1024,1024,1024,2048,0);
}

// Round 4
// 1446.833 us; speedup vs baseline: 4.8384x; 1.2004x over previous
//
#include <hip/hip_runtime.h>
#include <cstdint>

typedef _Float16 f16;
typedef __attribute__((ext_vector_type(4))) _Float16 f16x4;
typedef __attribute__((ext_vector_type(8))) _Float16 f16x8;
typedef __attribute__((ext_vector_type(4))) float f32x4;

#define GLDS16(gp, lp) __builtin_amdgcn_global_load_lds( \
  (const __attribute__((address_space(1))) void*)(gp), \
  (__attribute__((address_space(3))) void*)(lp), 16, 0, 0)

__device__ __forceinline__ int swzf(int row){ return (row + (row>>3)) & 7; }

// ---------------- row LayerNorm -> split f16 pair ----------------
template<int C>
__global__ __launch_bounds__(256) void lnf(const float* __restrict__ x, const float* __restrict__ g,
                                           const float* __restrict__ b, f16* __restrict__ o1, f16* __restrict__ o2){
  constexpr int PT = C/256;
  int row = blockIdx.x;
  const float* xr = x + (size_t)row*C;
  float v[PT]; float s = 0.f, s2 = 0.f;
  #pragma unroll
  for (int j=0;j<PT;j++){ v[j] = xr[threadIdx.x + j*256]; s += v[j]; s2 += v[j]*v[j]; }
  #pragma unroll
  for (int o=32;o;o>>=1){ s += __shfl_xor(s,o); s2 += __shfl_xor(s2,o); }
  __shared__ float ls[4], ls2[4];
  if ((threadIdx.x&63)==0){ ls[threadIdx.x>>6]=s; ls2[threadIdx.x>>6]=s2; }
  __syncthreads();
  s = ls[0]+ls[1]+ls[2]+ls[3]; s2 = ls2[0]+ls2[1]+ls2[2]+ls2[3];
  float mean = s*(1.f/C);
  float rstd = 1.0f/sqrtf(s2*(1.f/C) - mean*mean + 1e-5f);
  #pragma unroll
  for (int j=0;j<PT;j++){
    int c = threadIdx.x + j*256;
    float y = (v[j]-mean)*rstd*g[c] + b[c];
    f16 a = (f16)y;
    o1[(size_t)row*C + c] = a;
    o2[(size_t)row*C + c] = (f16)(y - (float)a);
  }
}

// ---------------- f32 -> split f16 pair ----------------
__global__ __launch_bounds__(256) void wsplit(const float* __restrict__ w, f16* __restrict__ o1,
                                              f16* __restrict__ o2, int n){
  for (int i = blockIdx.x*256 + threadIdx.x; i < n; i += gridDim.x*256){
    float x = w[i]; f16 a = (f16)x;
    o1[i] = a; o2[i] = (f16)(x - (float)a);
  }
}

// ---------------- pair transpose: (R,C) -> (C,R), re-split ----------------
__global__ __launch_bounds__(256) void tposeS(const f16* __restrict__ i1, const f16* __restrict__ i2,
                                              f16* __restrict__ o1, f16* __restrict__ o2, int R, int C){
  __shared__ float t[64][65];
  int r0 = blockIdx.y*64, c0 = blockIdx.x*64;
  int row = threadIdx.x>>2, seg = threadIdx.x&3;
  const f16* s1 = i1 + (size_t)(r0+row)*C + c0 + seg*16;
  const f16* s2 = i2 + (size_t)(r0+row)*C + c0 + seg*16;
  f16x8 a0 = *(const f16x8*)s1, a1 = *(const f16x8*)(s1+8);
  f16x8 b0 = *(const f16x8*)s2, b1 = *(const f16x8*)(s2+8);
  #pragma unroll
  for (int e=0;e<8;e++){
    t[row][seg*16+e]   = (float)a0[e] + (float)b0[e];
    t[row][seg*16+8+e] = (float)a1[e] + (float)b1[e];
  }
  __syncthreads();
  f16 p1[16], p2[16];
  #pragma unroll
  for (int e=0;e<16;e++){
    float x = t[seg*16+e][row];
    f16 a = (f16)x; p1[e] = a; p2[e] = (f16)(x - (float)a);
  }
  f16* d1 = o1 + (size_t)(c0+row)*R + r0 + seg*16;
  f16* d2 = o2 + (size_t)(c0+row)*R + r0 + seg*16;
  *(f16x8*)d1 = *(f16x8*)&p1[0]; *(f16x8*)(d1+8) = *(f16x8*)&p1[8];
  *(f16x8*)d2 = *(f16x8*)&p2[0]; *(f16x8*)(d2+8) = *(f16x8*)&p2[8];
}

// ---------------- invden from block partials ----------------
__global__ __launch_bounds__(256) void dinv(const float* __restrict__ denomP, float* __restrict__ invden, int n){
  int i = blockIdx.x*256 + threadIdx.x;
  if (i >= n) return;
  const float* p = denomP + (size_t)i*32;
  float s = 0.f;
  #pragma unroll
  for (int j=0;j<32;j++) s += p[j];
  invden[i] = 1.0f/s;
}

// ---------------- combine K-split partials -> split xi/as pair ----------------
__global__ __launch_bounds__(256) void ucomb(const float* __restrict__ part, f16* __restrict__ o1,
                                             f16* __restrict__ o2, int bhBase){
  int idx = blockIdx.x*256 + threadIdx.x;
  int n = idx & 255, m = (idx>>8) & 1023, zc = idx>>18;
  float v = part[((size_t)(zc*2+0)*1024 + m)*256 + n] +
            part[((size_t)(zc*2+1)*1024 + m)*256 + n];
  int bh = bhBase + zc, bb = bh>>2, h = bh&3;
  size_t off = ((size_t)(bb*1024+m))*1024 + (size_t)h*256 + n;
  f16 a = (f16)v;
  o1[off] = a; o2[off] = (f16)(v - (float)a);
}

// ---------------- split-f16 GEMM (f32-accurate), 128x128 tile, BK=32, 2-phase dbuf ----------------
// C[m,n] = sum_k A[m,k]*B[n,k]  (operands stored as f16 pairs; UPD: A = f32 E scaled+split at stage)
enum { M_PROJ=0, M_SCORE=1, M_UPD=2, M_OUT=3 };

template<int MODE>
__global__ __launch_bounds__(256,2) void sg(
    const f16* __restrict__ A1, const f16* __restrict__ A2,
    const f16* __restrict__ B1, const f16* __restrict__ B2,
    const float* __restrict__ Ef, const float* __restrict__ invden,
    const float* __restrict__ bias,
    float* __restrict__ Cf, f16* __restrict__ C1, f16* __restrict__ C2,
    float* __restrict__ denomP,
    int K, int ldA, int ldB, int ldC, int bhBase)
{
  __shared__ __align__(16) char lds[65536];   // 2 buffers x (A 16KB + B 16KB)
  const f16 *pA1=A1, *pA2=A2, *pB1=B1, *pB2=B2;
  const float* pE = Ef; const float* pInv = invden;
  float* pCf = Cf; f16 *pC1=C1, *pC2=C2; float* pDen = denomP;

  if (MODE==M_SCORE){
    int bh = bhBase + blockIdx.z, bb = bh>>2, h = bh&3;
    pA1 += (size_t)bb*1024*ldA + (size_t)h*256;
    pA2 += (size_t)bb*1024*ldA + (size_t)h*256;
    pB1 += (size_t)h*256;  pB2 += (size_t)h*256;
    pCf += (size_t)blockIdx.z*1024*4096;
    pDen += (size_t)blockIdx.z*1024*32;
  } else if (MODE==M_UPD){
    int z0 = blockIdx.z, zc = z0>>1, sp = z0&1;
    int bh = bhBase + zc, h = bh&3;
    pE  += (size_t)zc*1024*4096 + (size_t)sp*2048;   // E chunk + K-split col offset
    pB1 += (size_t)h*256*4096 + (size_t)sp*2048;     // K^T/V^T head slice
    pB2 += (size_t)h*256*4096 + (size_t)sp*2048;
    pInv += (size_t)zc*1024;
    pCf += (size_t)z0*1024*256;                      // f32 partial
  }

  const int tid = threadIdx.x;
  const int lane = tid & 63, w = tid >> 6;
  const int wr = w>>1, wc = w&1;
  const int g = lane>>4, li = lane&15;
  const int m0 = blockIdx.y*128, n0 = blockIdx.x*128;

  f32x4 acc[4][4] = {};

  // ---- UPD A-prefetch pipeline state ----
  f32x4 rA[4]; float invi[4]; int rowA[4];
  const int subA = tid & 7;
  if (MODE==M_UPD){
    #pragma unroll
    for (int it=0;it<4;it++){
      rowA[it] = (tid + it*256)>>3;
      invi[it] = pInv[m0 + rowA[it]];
    }
  }
  auto loadA = [&](int k0){
    #pragma unroll
    for (int it=0;it<4;it++)
      rA[it] = *(const f32x4*)(pE + (size_t)(m0+rowA[it])*ldA + k0 + subA*4);
  };
  auto writeA = [&](char* base){   // scale by invden, split, swizzled ds_write
    int oct = subA>>1, lo = (subA&1)*8;
    #pragma unroll
    for (int it=0;it<4;it++){
      f32x4 p = rA[it]*invi[it];
      f16x4 h1, h2;
      #pragma unroll
      for (int j=0;j<4;j++){ f16 a=(f16)p[j]; h1[j]=a; h2[j]=(f16)(p[j]-(float)a); }
      int s = swzf(rowA[it]);
      char* rb = base + rowA[it]*128;
      *(f16x4*)(rb + ((oct^s)<<4) + lo)     = h1;
      *(f16x4*)(rb + (((4+oct)^s)<<4) + lo) = h2;
    }
  };
  auto stageA = [&](int k0, char* base){
    #pragma unroll
    for (int it=0; it<4; it++){
      int c = tid + it*256, row = c>>3, sub = c&7, q = sub ^ swzf(row);
      const f16* src = ((q&4)?pA2:pA1) + (size_t)(m0+row)*ldA + k0 + (q&3)*8;
      GLDS16(src, base + c*16);
    }
  };
  auto stageB = [&](int k0, char* base){
    #pragma unroll
    for (int it=0; it<4; it++){
      int c = tid + it*256, row = c>>3, sub = c&7, q = sub ^ swzf(row);
      const f16* src = ((q&4)?pB2:pB1) + (size_t)(n0+row)*ldB + k0 + (q&3)*8;
      GLDS16(src, base + 16384 + c*16);
    }
  };

  const int nt = K >> 5;
  char* buf0 = lds;
  char* buf1 = lds + 32768;

  // ---- prologue ----
  if (MODE==M_UPD){
    loadA(0);
    stageB(0, buf0);
    asm volatile("s_waitcnt vmcnt(0)" ::: "memory");
    writeA(buf0);
    if (nt > 1) loadA(32);                  // A(1) in flight across barrier
    asm volatile("s_waitcnt lgkmcnt(0)" ::: "memory");
    __builtin_amdgcn_s_barrier();
  } else {
    stageA(0, buf0); stageB(0, buf0);
    asm volatile("s_waitcnt vmcnt(0)" ::: "memory");
    __builtin_amdgcn_s_barrier();
  }

  int cur = 0;
  for (int t = 0; t < nt; t++){
    char* bc = cur ? buf1 : buf0;
    char* bn = cur ? buf0 : buf1;
    bool pre = (t+1 < nt);
    bool deep = (t+2 < nt);
    if (MODE==M_UPD){
      if (pre){
        writeA(bn);                          // uses rA(t+1); compiler waits its loads
        stageB((t+1)<<5, bn);                // GLDS first (drained at bottom)
        if (deep) loadA((t+2)<<5);           // stays in flight across barrier
      }
    } else {
      if (pre){ stageA((t+1)<<5, bn); stageB((t+1)<<5, bn); }
    }
    // ---- fragments + 48 MFMA from current buffer ----
    f16x8 a1[4], a2[4], b1v[4], b2v[4];
    #pragma unroll
    for (int mi=0;mi<4;mi++){
      int r = wr*64 + mi*16 + li, s = swzf(r);
      const char* p = bc + r*128;
      a1[mi] = *(const f16x8*)(p + ((g^s)<<4));
      a2[mi] = *(const f16x8*)(p + (((4+g)^s)<<4));
    }
    #pragma unroll
    for (int nj=0;nj<4;nj++){
      int r = wc*64 + nj*16 + li, s = swzf(r);
      const char* p = bc + 16384 + r*128;
      b1v[nj] = *(const f16x8*)(p + ((g^s)<<4));
      b2v[nj] = *(const f16x8*)(p + (((4+g)^s)<<4));
    }
    #pragma unroll
    for (int mi=0;mi<4;mi++)
      #pragma unroll
      for (int nj=0;nj<4;nj++){
        acc[mi][nj] = __builtin_amdgcn_mfma_f32_16x16x32_f16(a1[mi], b1v[nj], acc[mi][nj],0,0,0);
        acc[mi][nj] = __builtin_amdgcn_mfma_f32_16x16x32_f16(a2[mi], b1v[nj], acc[mi][nj],0,0,0);
        acc[mi][nj] = __builtin_amdgcn_mfma_f32_16x16x32_f16(a1[mi], b2v[nj], acc[mi][nj],0,0,0);
      }
    // ---- one counted wait + one barrier per K-step ----
    if (MODE==M_UPD && deep)
      asm volatile("s_waitcnt vmcnt(4) lgkmcnt(0)" ::: "memory");  // drain GLDS-B, keep A-prefetch
    else
      asm volatile("s_waitcnt vmcnt(0) lgkmcnt(0)" ::: "memory");
    __builtin_amdgcn_s_barrier();
    cur ^= 1;
  }

  // ---- epilogue ----
  float rs[4][4];
  if (MODE==M_SCORE){
    #pragma unroll
    for (int mi=0;mi<4;mi++)
      #pragma unroll
      for (int r=0;r<4;r++) rs[mi][r]=0.f;
  }
  #pragma unroll
  for (int mi=0;mi<4;mi++){
    int mrow = m0 + wr*64 + mi*16 + g*4;
    #pragma unroll
    for (int nj=0;nj<4;nj++){
      int n = n0 + wc*64 + nj*16 + li;
      f32x4 a = acc[mi][nj];
      if (MODE==M_PROJ){
        float bvv = bias[n];
        #pragma unroll
        for (int r=0;r<4;r++){
          float y = a[r]+bvv; f16 y1=(f16)y;
          pC1[(size_t)(mrow+r)*ldC + n] = y1;
          pC2[(size_t)(mrow+r)*ldC + n] = (f16)(y-(float)y1);
        }
      } else if (MODE==M_SCORE){
        #pragma unroll
        for (int r=0;r<4;r++){
          float e = expf(0.5f*a[r]);
          pCf[(size_t)(mrow+r)*ldC + n] = e;
          rs[mi][r] += e;
        }
      } else if (MODE==M_UPD){
        #pragma unroll
        for (int r=0;r<4;r++) pCf[(size_t)(mrow+r)*ldC + n] = a[r];
      } else {
        float bvv = bias[n];
        #pragma unroll
        for (int r=0;r<4;r++) pCf[(size_t)(mrow+r)*ldC + n] = a[r]+bvv;
      }
    }
  }
  if (MODE==M_SCORE){
    #pragma unroll
    for (int mi=0;mi<4;mi++)
      #pragma unroll
      for (int r=0;r<4;r++){
        float s = rs[mi][r];
        s += __shfl_xor(s,1); s += __shfl_xor(s,2); s += __shfl_xor(s,4); s += __shfl_xor(s,8);
        rs[mi][r] = s;
      }
    __syncthreads();
    float* sb = (float*)lds;
    if (li==0){
      #pragma unroll
      for (int mi=0;mi<4;mi++)
        #pragma unroll
        for (int r=0;r<4;r++)
          sb[wc*128 + wr*64 + mi*16 + g*4 + r] = rs[mi][r];
    }
    __syncthreads();
    if (tid < 128) pDen[(size_t)(m0+tid)*32 + blockIdx.x] = sb[tid] + sb[128+tid];
  }
}

// ---------------- launch ----------------
extern "C" void kernel_launch(void* const* d_in, const int* in_sizes, int n_in,
                              void* d_out, int out_size, void* d_ws, size_t ws_size,
                              hipStream_t stream)
{
  const float* hidden   = (const float*)d_in[0];
  const float* memoryp  = (const float*)d_in[1];
  const float* Wq = (const float*)d_in[2];  const float* bq = (const float*)d_in[3];
  const float* Wk = (const float*)d_in[4];  const float* bk = (const float*)d_in[5];
  const float* Wv = (const float*)d_in[6];  const float* bv = (const float*)d_in[7];
  const float* Wo = (const float*)d_in[8];  const float* bo = (const float*)d_in[9];
  const float* g_stored = (const float*)d_in[10]; const float* b_stored = (const float*)d_in[11];
  const float* g_state  = (const float*)d_in[12]; const float* b_state  = (const float*)d_in[13];
  const float* g_proj   = (const float*)d_in[14]; const float* b_proj   = (const float*)d_in[15];

  char* ws = (char*)d_ws;
  size_t off = 0;
  auto alloc = [&](size_t bytes)->char* {
    char* p = ws + off; off += (bytes + 255) & ~(size_t)255; return p;
  };
  const size_t E16 = 4096ull*1024*2;
  f16* xi1 = (f16*)alloc(E16);  f16* xi2 = (f16*)alloc(E16);
  f16* k1  = (f16*)alloc(E16);  f16* k2  = (f16*)alloc(E16);
  f16* kt1 = (f16*)alloc(E16);  f16* kt2 = (f16*)alloc(E16);
  f16* vt1 = (f16*)alloc(E16);  f16* vt2 = (f16*)alloc(E16);
  f16* as1 = (f16*)alloc(E16);  f16* as2 = (f16*)alloc(E16);
  f16* wq1 = (f16*)alloc(1024ull*2048*2); f16* wq2 = (f16*)alloc(1024ull*2048*2);
  f16* wk1 = (f16*)alloc(1024ull*768*2);  f16* wk2 = (f16*)alloc(1024ull*768*2);
  f16* wv1 = (f16*)alloc(1024ull*768*2);  f16* wv2 = (f16*)alloc(1024ull*768*2);
  f16* wo1 = (f16*)alloc(2048ull*1024*2); f16* wo2 = (f16*)alloc(2048ull*1024*2);
  size_t persist = off;

  size_t o2 = persist;
  auto alloc2 = [&](size_t bytes)->char* {
    char* p = ws + o2; o2 += (bytes + 255) & ~(size_t)255; return p;
  };
  f16* sn1 = (f16*)alloc2(4096ull*2048*2); f16* sn2 = (f16*)alloc2(4096ull*2048*2);
  f16* st1 = (f16*)alloc2(4096ull*768*2);  f16* st2 = (f16*)alloc2(4096ull*768*2);
  f16* pj1 = (f16*)alloc2(4096ull*768*2);  f16* pj2 = (f16*)alloc2(4096ull*768*2);
  f16* v1  = (f16*)alloc2(E16);            f16* v2  = (f16*)alloc2(E16);

  int nbh = 8;
  while (nbh > 1){
    size_t need = persist + (size_t)nbh*(1024ull*4096*4) + (size_t)nbh*(2*1024*256*4)
                + (size_t)nbh*(1024*32*4) + (size_t)nbh*1024*4 + 4096;
    if (need <= ws_size) break;
    nbh >>= 1;
  }
  int NC = 16 / nbh;
  o2 = persist;
  float* E      = (float*)alloc2((size_t)nbh*1024*4096*4);
  float* part   = (float*)alloc2((size_t)nbh*2*1024*256*4);
  float* denomP = (float*)alloc2((size_t)nbh*1024*32*4);
  float* invden = (float*)alloc2((size_t)nbh*1024*4);

  // 1) layernorms -> split pairs
  lnf<2048><<<4096, 256, 0, stream>>>(hidden,  g_state,  b_state,  sn1, sn2);
  lnf<768> <<<4096, 256, 0, stream>>>(memoryp, g_stored, b_stored, st1, st2);
  lnf<768> <<<4096, 256, 0, stream>>>(memoryp, g_proj,   b_proj,   pj1, pj2);
  // 2) weight splits
  wsplit<<<2048, 256, 0, stream>>>(Wq, wq1, wq2, 1024*2048);
  wsplit<<<1024, 256, 0, stream>>>(Wk, wk1, wk2, 1024*768);
  wsplit<<<1024, 256, 0, stream>>>(Wv, wv1, wv2, 1024*768);
  wsplit<<<2048, 256, 0, stream>>>(Wo, wo1, wo2, 2048*1024);
  // 3) projections (NT): q->xi pair, k->k pair, v->v pair
  sg<M_PROJ><<<dim3(8,32,1),256,0,stream>>>(sn1,sn2, wq1,wq2, nullptr,nullptr, bq, nullptr, xi1,xi2, nullptr, 2048,2048,2048,1024,0);
  sg<M_PROJ><<<dim3(8,32,1),256,0,stream>>>(st1,st2, wk1,wk2, nullptr,nullptr, bk, nullptr, k1,k2,  nullptr,  768, 768, 768,1024,0);
  sg<M_PROJ><<<dim3(8,32,1),256,0,stream>>>(pj1,pj2, wv1,wv2, nullptr,nullptr, bv, nullptr, v1,v2,  nullptr,  768, 768, 768,1024,0);
  // 4) transposes: (4096x1024) -> (1024x4096), re-split
  tposeS<<<dim3(16,64),256,0,stream>>>(k1,k2, kt1,kt2, 4096,1024);
  tposeS<<<dim3(16,64),256,0,stream>>>(v1,v2, vt1,vt2, 4096,1024);
  // 5) Hopfield rounds: 3 updates with K^T, readout with V^T
  for (int r = 0; r < 4; r++){
    const f16* Bt1 = (r < 3) ? kt1 : vt1;
    const f16* Bt2 = (r < 3) ? kt2 : vt2;
    f16* d1 = (r < 3) ? xi1 : as1;
    f16* d2 = (r < 3) ? xi2 : as2;
    for (int c = 0; c < NC; c++){
      int bhBase = c*nbh;
      sg<M_SCORE><<<dim3(32,8,nbh),256,0,stream>>>(xi1,xi2, k1,k2, nullptr,nullptr, nullptr, E, nullptr,nullptr, denomP, 256,1024,1024,4096, bhBase);
      dinv<<<(nbh*1024+255)/256,256,0,stream>>>(denomP, invden, nbh*1024);
      sg<M_UPD><<<dim3(2,8,nbh*2),256,0,stream>>>(nullptr,nullptr, Bt1,Bt2, E, invden, nullptr, part, nullptr,nullptr, nullptr, 2048,4096,4096,256, bhBase);
      ucomb<<<nbh*1024,256,0,stream>>>(part, d1, d2, bhBase);
    }
  }
  // 6) output projection -> f32 d_out
  sg<M_OUT><<<dim3(16,32,1),256,0,stream>>>(as1,as2, wo1,wo2, nullptr,nullptr, bo, (float*)d_out, nullptr,nullptr, nullptr, 1024,1024,1024,2048,0);
}